// Round 7
// baseline (104.265 us; speedup 1.0000x reference)
//
#include <hip/hip_runtime.h>
#include <hip/hip_bf16.h>
#include <math.h>

#define BN_EPS 1e-5f
#define B_  96
#define N_  20
#define D_  2048
#define K_  10
#define M_  (B_*N_)   // 1920
#define R_  (2*D_)    // 4096

typedef __attribute__((ext_vector_type(8))) short bf16x8;
typedef __attribute__((ext_vector_type(4))) float f32x4;
typedef __attribute__((ext_vector_type(8))) unsigned short ushort8;

static __device__ __forceinline__ unsigned short f2bf(float f) {
  unsigned int u = __builtin_bit_cast(unsigned int, f);
  u = u + 0x7fffu + ((u >> 16) & 1u);   // RNE (finite inputs only)
  return (unsigned short)(u >> 16);
}

#define GLOAD_LDS16(g, l) \
  __builtin_amdgcn_global_load_lds((const __attribute__((address_space(1))) void*)(g), \
                                   (__attribute__((address_space(3))) void*)(l), 16, 0, 0)

// ------- kernel 1: heterogeneous prep --------------------------------------
// blocks 0..95: knn (symmetric pairs) + cast x->bf16 for batch b (latency-bound)
// blocks 96..511: grid-stride cast+repack conv_w -> Wn bf16 (memory-bound)
// Fusing lets the two phases overlap instead of serializing.
__global__ __launch_bounds__(512) void prep_kernel(const float* __restrict__ x,
                                                   const float* __restrict__ cw,
                                                   int* __restrict__ nn_idx,
                                                   unsigned short* __restrict__ Xb,
                                                   unsigned short* __restrict__ Wn)
{
  int t = threadIdx.x;
  if (blockIdx.x >= B_) {
    // ---- cast_w part: Wn[r][k], r=2*o+h: h=0 -> cw[o][k], h=1 -> cw[o][2048+k]
    int cb = blockIdx.x - B_;                    // 0..415
    for (int i = cb*512 + t; i < R_*D_/8; i += 416*512) {
      int r = i >> 8;                            // 256 chunks of 8 per row
      int k = (i & 255) * 8;
      const float* src = cw + (size_t)(r >> 1) * R_ + ((r & 1) << 11) + k;
      float4 a = *(const float4*)src, c = *(const float4*)(src + 4);
      ushort8 o = { f2bf(a.x), f2bf(a.y), f2bf(a.z), f2bf(a.w),
                    f2bf(c.x), f2bf(c.y), f2bf(c.z), f2bf(c.w) };
      *((ushort8*)Wn + i) = o;
    }
    return;
  }
  // ---- knn part ----
  int b = blockIdx.x, w = t >> 6, lane = t & 63;
  __shared__ float innr[N_*N_];
  __shared__ float adjl[N_*N_];
  const float* xb = x + (size_t)b * N_ * D_;
  for (int p = w; p < (N_*(N_+1))/2; p += 8) {   // 210 unordered pairs
    int n = 0;
    while ((n+1)*N_ - ((n+1)*n)/2 <= p) ++n;
    int m = n + (p - (n*N_ - (n*(n-1))/2));
    const float4* xn = (const float4*)(xb + n * D_);
    const float4* xm = (const float4*)(xb + m * D_);
    float s = 0.f;
    #pragma unroll
    for (int c = lane; c < D_/4; c += 64) {
      float4 a = xn[c], v = xm[c];
      s = fmaf(a.x, v.x, fmaf(a.y, v.y, fmaf(a.z, v.z, fmaf(a.w, v.w, s))));
    }
    #pragma unroll
    for (int off = 32; off > 0; off >>= 1)
      s += __shfl_xor(s, off, 64);
    if (lane == 0) { innr[n*N_+m] = s; innr[m*N_+n] = s; }
  }
  __syncthreads();
  for (int p = t; p < N_*N_; p += 512) {
    int n = p / N_, m = p % N_;
    adjl[p] = innr[n*N_+n] + innr[m*N_+m] - 2.f * innr[p];
  }
  __syncthreads();
  if (t < N_) {
    int n = t;
    unsigned mask = 0;
    for (int it = 0; it < K_; ++it) {
      float bv = INFINITY; int bi = 0;
      for (int m = 0; m < N_; ++m) {
        if (!((mask >> m) & 1u)) {
          float v = adjl[n*N_+m];
          if (v < bv) { bv = v; bi = m; }
        }
      }
      mask |= 1u << bi;
      nn_idx[(b*N_ + n)*K_ + it] = bi;
    }
  }
  // fused cast of this batch's x slice -> bf16
  unsigned short* xo = Xb + (size_t)b * N_ * D_;
  for (int i = t; i < N_*D_/8; i += 512) {
    const float4* src = (const float4*)xb + (size_t)i * 2;
    float4 a = src[0], c = src[1];
    ushort8 o = { f2bf(a.x), f2bf(a.y), f2bf(a.z), f2bf(a.w),
                  f2bf(c.x), f2bf(c.y), f2bf(c.z), f2bf(c.w) };
    *((ushort8*)xo + i) = o;
  }
}

// ---------------- kernel 2: fused bf16 MFMA GEMM + BN/ReLU/neighbor-max ----
// Tile: 80 rows (4 batches) x 128 cols (64 outputs, P/Q interleaved).
// T3 minimum 2-phase: BK=32, full LDS double-buffer; issue tile t+1's
// global_load_lds BEFORE computing tile t; one vmcnt(0)+barrier per K-step
// (the __syncthreads drain). LDS total 44160 B -> still 3 blocks/CU.
// Chunk-XOR swizzle (both-sides-or-neither): 4 chunks/row, kc ^= row&3.
__global__ __launch_bounds__(256, 4) void fused_gemm(
    const unsigned short* __restrict__ Xb, const unsigned short* __restrict__ Wn,
    const int* __restrict__ nn_idx, const float* __restrict__ conv_b,
    const float* __restrict__ gamma, const float* __restrict__ beta,
    const float* __restrict__ mean, const float* __restrict__ var,
    float* __restrict__ out)
{
  __shared__ __align__(16) char smem[44160];
  unsigned short* As = (unsigned short*)smem;   // buf: As[80][32] 5120B + Bs[128][32] 8192B
  float* Cl  = (float*)smem;                    // [80][128] f32, 40960 B (epilogue reuse)
  int*   idxl = (int*)(smem + 40960);           // [4][200] int, 3200 B (disjoint)

  // bijective XCD-chunk swizzle (768 % 8 == 0)
  int flat = blockIdx.y * 24 + blockIdx.x;
  int nf = (flat & 7) * 96 + (flat >> 3);
  int bx = nf % 24, by = nf / 24;

  int t = threadIdx.x, lane = t & 63, w = t >> 6;  // w = wr (0..3)
  int m0 = bx * 80, b0 = bx * 4;
  int r0 = by * 128, o0 = by * 64;
  int rowsel = lane & 15, ksel = lane >> 4;        // ksel 0..3: 8-elem slot in 32

  for (int i = t; i < 4*N_*K_; i += 256) idxl[i] = nn_idx[b0*N_*K_ + i];

  f32x4 acc[5][2] = {};

  // stage tile (k0) into buffer bufsel; LDS dest linear, global src chunk-XOR'd
  auto stage = [&](int bufsel, int k0) {
    unsigned short* Asb = As + bufsel * 6656;      // 13312 B per buffer
    unsigned short* Bsb = Asb + 2560;
    {
      int row = t >> 2, kc = t & 3;                // A chunks 0..255
      GLOAD_LDS16(Xb + (size_t)(m0 + row) * D_ + k0 + ((kc ^ (row & 3)) << 3),
                  Asb + t*8);
      if (t < 64) {                                // A chunks 256..319 (wave 0)
        int fl = 256 + t, row2 = fl >> 2, kc2 = fl & 3;
        GLOAD_LDS16(Xb + (size_t)(m0 + row2) * D_ + k0 + ((kc2 ^ (row2 & 3)) << 3),
                    Asb + fl*8);
      }
    }
    #pragma unroll
    for (int i = 0; i < 2; ++i) {                  // B chunks 0..511
      int fl = i*256 + t;
      int row = fl >> 2, kc = fl & 3;
      GLOAD_LDS16(Wn + (size_t)(r0 + row) * D_ + k0 + ((kc ^ (row & 3)) << 3),
                  Bsb + fl*8);
    }
  };

  auto compute = [&](int bufsel) {
    unsigned short* Asb = As + bufsel * 6656;
    unsigned short* Bsb = Asb + 2560;
    int swz = (ksel ^ (rowsel & 3)) << 3;          // row-tile offsets are 16-mult
    bf16x8 a[5], bv[2];
    #pragma unroll
    for (int mi = 0; mi < 5; ++mi)
      a[mi] = *(const bf16x8*)(Asb + (mi*16 + rowsel)*32 + swz);
    #pragma unroll
    for (int ri = 0; ri < 2; ++ri)
      bv[ri] = *(const bf16x8*)(Bsb + (w*32 + ri*16 + rowsel)*32 + swz);
    #pragma unroll
    for (int mi = 0; mi < 5; ++mi)
      #pragma unroll
      for (int ri = 0; ri < 2; ++ri)
        acc[mi][ri] = __builtin_amdgcn_mfma_f32_16x16x32_bf16(a[mi], bv[ri], acc[mi][ri], 0, 0, 0);
  };

  stage(0, 0);
  __syncthreads();                                 // vmcnt(0)+barrier: tile 0 ready
  for (int kt = 0; kt < D_/32; kt += 2) {
    stage(1, (kt+1)*32);                           // prefetch odd tile
    compute(0);                                    // compute even tile
    __syncthreads();                               // drain prefetch + buf0 reads done
    if (kt + 2 < D_/32) stage(0, (kt+2)*32);       // prefetch next even tile
    compute(1);                                    // compute odd tile
    __syncthreads();
  }

  // ---- fused epilogue ----
  #pragma unroll
  for (int mi = 0; mi < 5; ++mi)
    #pragma unroll
    for (int ri = 0; ri < 2; ++ri)
      #pragma unroll
      for (int rg = 0; rg < 4; ++rg)
        Cl[(mi*16 + ksel*4 + rg)*128 + w*32 + ri*16 + rowsel] = acc[mi][ri][rg];
  __syncthreads();

  int bb = w, oo = lane;               // (batch-in-tile, output-in-tile)
  int og = o0 + oo;
  float invv  = gamma[og] / sqrtf(var[og] + BN_EPS);
  float shift = fmaf(-mean[og], invv, beta[og]);
  float bias  = conv_b[og];
  float best = 0.f;                    // relu identity
  int rbase = bb * N_;
  for (int n = 0; n < N_; ++n) {
    float Pv = Cl[(rbase + n)*128 + oo*2];
    float Qn = Cl[(rbase + n)*128 + oo*2 + 1];
    float aa = Pv - Qn + bias;
    const int* ix = idxl + bb*N_*K_ + n*K_;
    #pragma unroll
    for (int kk = 0; kk < K_; ++kk) {
      int j = ix[kk];
      float v = fmaf(aa + Cl[(rbase + j)*128 + oo*2 + 1], invv, shift);
      best = fmaxf(best, v);
    }
  }
  out[(size_t)(b0 + bb) * D_ + og] = best;
}

extern "C" void kernel_launch(void* const* d_in, const int* in_sizes, int n_in,
                              void* d_out, int out_size, void* d_ws, size_t ws_size,
                              hipStream_t stream)
{
  const float* x      = (const float*)d_in[0];
  const float* conv_w = (const float*)d_in[1];
  const float* conv_b = (const float*)d_in[2];
  const float* gamma  = (const float*)d_in[3];
  const float* beta   = (const float*)d_in[4];
  const float* mean   = (const float*)d_in[5];
  const float* var    = (const float*)d_in[6];

  // workspace: nn_idx 76800 B | Xb bf16 7864320 B | Wn bf16 16777216 B  (24.7 MB)
  int* nn_idx = (int*)d_ws;
  unsigned short* Xb = (unsigned short*)((char*)d_ws + 76800);
  unsigned short* Wn = (unsigned short*)((char*)d_ws + 76800 + (size_t)M_*D_*2);

  prep_kernel<<<B_ + 416, 512, 0, stream>>>(x, conv_w, nn_idx, Xb, Wn);
  fused_gemm<<<dim3(24, 32), 256, 0, stream>>>(
      Xb, Wn, nn_idx, conv_b, gamma, beta, mean, var, (float*)d_out);
}

// Round 8
// 77.464 us; speedup vs baseline: 1.3460x; 1.3460x over previous
//
#include <hip/hip_runtime.h>
#include <hip/hip_bf16.h>
#include <math.h>

#define BN_EPS 1e-5f
#define B_  96
#define N_  20
#define D_  2048
#define K_  10
#define M_  (B_*N_)   // 1920
#define R_  (2*D_)    // 4096

typedef __attribute__((ext_vector_type(8))) short bf16x8;
typedef __attribute__((ext_vector_type(4))) float f32x4;
typedef __attribute__((ext_vector_type(8))) unsigned short ushort8;

static __device__ __forceinline__ unsigned short f2bf(float f) {
  unsigned int u = __builtin_bit_cast(unsigned int, f);
  u = u + 0x7fffu + ((u >> 16) & 1u);   // RNE (finite inputs only)
  return (unsigned short)(u >> 16);
}

#define GLOAD_LDS16(g, l) \
  __builtin_amdgcn_global_load_lds((const __attribute__((address_space(1))) void*)(g), \
                                   (__attribute__((address_space(3))) void*)(l), 16, 0, 0)

// ------- kernel 1: heterogeneous prep --------------------------------------
// blocks 0..95: knn + cast x->bf16 for batch b. Row-grouped pairs: wave w owns
// rows {w, 15-w, 16+w(w<4)} (25-29 pairs each); row n cached in registers, 4
// independent accumulators -> breaks the round-7 serial-chain latency problem.
// blocks 96..511: grid-stride cast+repack conv_w -> Wn bf16 (memory-bound).
__global__ __launch_bounds__(512) void prep_kernel(const float* __restrict__ x,
                                                   const float* __restrict__ cw,
                                                   int* __restrict__ nn_idx,
                                                   unsigned short* __restrict__ Xb,
                                                   unsigned short* __restrict__ Wn)
{
  int t = threadIdx.x;
  if (blockIdx.x >= B_) {
    // ---- cast_w part: Wn[r][k], r=2*o+h: h=0 -> cw[o][k], h=1 -> cw[o][2048+k]
    int cb = blockIdx.x - B_;                    // 0..415
    for (int i = cb*512 + t; i < R_*D_/8; i += 416*512) {
      int r = i >> 8;                            // 256 chunks of 8 per row
      int k = (i & 255) * 8;
      const float* src = cw + (size_t)(r >> 1) * R_ + ((r & 1) << 11) + k;
      float4 a = *(const float4*)src, c = *(const float4*)(src + 4);
      ushort8 o = { f2bf(a.x), f2bf(a.y), f2bf(a.z), f2bf(a.w),
                    f2bf(c.x), f2bf(c.y), f2bf(c.z), f2bf(c.w) };
      *((ushort8*)Wn + i) = o;
    }
    return;
  }
  // ---- knn part ----
  int b = blockIdx.x, w = t >> 6, lane = t & 63;
  __shared__ float innr[N_*N_];
  __shared__ float adjl[N_*N_];
  const float* xb = x + (size_t)b * N_ * D_;
  int rows[3] = { w, 15 - w, (w < 4) ? 16 + w : -1 };
  #pragma unroll
  for (int ri = 0; ri < 3; ++ri) {
    int n = rows[ri];
    if (n < 0) continue;
    const float4* xnp = (const float4*)(xb + n * D_);
    float4 xn[8];
    #pragma unroll
    for (int j = 0; j < 8; ++j) xn[j] = xnp[lane + 64*j];
    for (int m = n; m < N_; ++m) {
      const float4* xmp = (const float4*)(xb + m * D_);
      float s0 = 0.f, s1 = 0.f, s2 = 0.f, s3 = 0.f;
      #pragma unroll
      for (int j = 0; j < 8; ++j) {
        float4 v = xmp[lane + 64*j];
        float d = fmaf(xn[j].x, v.x, fmaf(xn[j].y, v.y,
                  fmaf(xn[j].z, v.z, xn[j].w * v.w)));
        if      ((j&3)==0) s0 += d;
        else if ((j&3)==1) s1 += d;
        else if ((j&3)==2) s2 += d;
        else               s3 += d;
      }
      float s = (s0 + s1) + (s2 + s3);
      #pragma unroll
      for (int off = 32; off > 0; off >>= 1)
        s += __shfl_xor(s, off, 64);
      if (lane == 0) { innr[n*N_+m] = s; innr[m*N_+n] = s; }
    }
  }
  __syncthreads();
  for (int p = t; p < N_*N_; p += 512) {
    int n = p / N_, m = p % N_;
    adjl[p] = innr[n*N_+n] + innr[m*N_+m] - 2.f * innr[p];
  }
  __syncthreads();
  if (t < N_) {
    int n = t;
    unsigned mask = 0;
    for (int it = 0; it < K_; ++it) {
      float bv = INFINITY; int bi = 0;
      for (int m = 0; m < N_; ++m) {
        if (!((mask >> m) & 1u)) {
          float v = adjl[n*N_+m];
          if (v < bv) { bv = v; bi = m; }
        }
      }
      mask |= 1u << bi;
      nn_idx[(b*N_ + n)*K_ + it] = bi;
    }
  }
  // fused cast of this batch's x slice -> bf16
  unsigned short* xo = Xb + (size_t)b * N_ * D_;
  for (int i = t; i < N_*D_/8; i += 512) {
    const float4* src = (const float4*)xb + (size_t)i * 2;
    float4 a = src[0], c = src[1];
    ushort8 o = { f2bf(a.x), f2bf(a.y), f2bf(a.z), f2bf(a.w),
                  f2bf(c.x), f2bf(c.y), f2bf(c.z), f2bf(c.w) };
    *((ushort8*)xo + i) = o;
  }
}

// ---------------- kernel 2: fused bf16 MFMA GEMM + BN/ReLU/neighbor-max ----
// EXACT round-6 structure (proven 46.2 us): 80x128 tile, BK=64, 4 waves,
// grid 24x32=768=3/CU, chunk-XOR swizzle with 3 row bits (kc ^ row&7).
// Round-7 lesson: BK=32 halves the XOR spread (2 row bits) -> 4.7x conflicts.
__global__ __launch_bounds__(256, 4) void fused_gemm(
    const unsigned short* __restrict__ Xb, const unsigned short* __restrict__ Wn,
    const int* __restrict__ nn_idx, const float* __restrict__ conv_b,
    const float* __restrict__ gamma, const float* __restrict__ beta,
    const float* __restrict__ mean, const float* __restrict__ var,
    float* __restrict__ out)
{
  __shared__ __align__(16) char smem[44160];
  unsigned short* As = (unsigned short*)smem;             // [80][64] bf16, 10240 B
  unsigned short* Bs = (unsigned short*)(smem + 10240);   // [128][64] bf16, 16384 B (ends 26624)
  float* Cl  = (float*)smem;                              // [80][128] f32, 40960 B (reuses stage)
  int*   idxl = (int*)(smem + 40960);                     // [4][200] int, 3200 B (disjoint)

  // bijective XCD-chunk swizzle (768 % 8 == 0): XCD c owns 4 consecutive W-panels
  int flat = blockIdx.y * 24 + blockIdx.x;
  int nf = (flat & 7) * 96 + (flat >> 3);
  int bx = nf % 24, by = nf / 24;

  int t = threadIdx.x, lane = t & 63, w = t >> 6;  // w = wr (0..3)
  int m0 = bx * 80, b0 = bx * 4;
  int r0 = by * 128, o0 = by * 64;
  int rowsel = lane & 15, ksel = lane >> 4;

  for (int i = t; i < 4*N_*K_; i += 256) idxl[i] = nn_idx[b0*N_*K_ + i];

  f32x4 acc[5][2] = {};

  for (int k0 = 0; k0 < D_; k0 += 64) {
    #pragma unroll
    for (int i = 0; i < 3; ++i) {                 // A: 80*8 = 640 16B-chunks
      int fl = i*256 + t;
      if (fl < 640) {
        int row = fl >> 3, kc = fl & 7;
        GLOAD_LDS16(Xb + (size_t)(m0 + row) * D_ + k0 + ((kc ^ (row & 7)) << 3),
                    As + fl*8);
      }
    }
    #pragma unroll
    for (int i = 0; i < 4; ++i) {                 // B: 128*8 = 1024 16B-chunks
      int fl = i*256 + t;
      int row = fl >> 3, kc = fl & 7;
      GLOAD_LDS16(Wn + (size_t)(r0 + row) * D_ + k0 + ((kc ^ (row & 7)) << 3),
                  Bs + fl*8);
    }
    __syncthreads();
    #pragma unroll
    for (int ks = 0; ks < 2; ++ks) {
      int swz = ((ks*4 + ksel) ^ (rowsel & 7)) << 3;   // tile offsets are 16-multiples
      bf16x8 a[5], bfr[2];
      #pragma unroll
      for (int mi = 0; mi < 5; ++mi)
        a[mi] = *(const bf16x8*)(As + (mi*16 + rowsel)*64 + swz);
      #pragma unroll
      for (int ri = 0; ri < 2; ++ri)
        bfr[ri] = *(const bf16x8*)(Bs + (w*32 + ri*16 + rowsel)*64 + swz);
      #pragma unroll
      for (int mi = 0; mi < 5; ++mi)
        #pragma unroll
        for (int ri = 0; ri < 2; ++ri)
          acc[mi][ri] = __builtin_amdgcn_mfma_f32_16x16x32_bf16(a[mi], bfr[ri], acc[mi][ri], 0, 0, 0);
    }
    __syncthreads();
  }

  // ---- fused epilogue ----
  #pragma unroll
  for (int mi = 0; mi < 5; ++mi)
    #pragma unroll
    for (int ri = 0; ri < 2; ++ri)
      #pragma unroll
      for (int rg = 0; rg < 4; ++rg)
        Cl[(mi*16 + ksel*4 + rg)*128 + w*32 + ri*16 + rowsel] = acc[mi][ri][rg];
  __syncthreads();

  int bb = w, oo = lane;               // (batch-in-tile, output-in-tile)
  int og = o0 + oo;
  float invv  = gamma[og] / sqrtf(var[og] + BN_EPS);
  float shift = fmaf(-mean[og], invv, beta[og]);
  float bias  = conv_b[og];
  float best = 0.f;                    // relu identity
  int rbase = bb * N_;
  for (int n = 0; n < N_; ++n) {
    float Pv = Cl[(rbase + n)*128 + oo*2];
    float Qn = Cl[(rbase + n)*128 + oo*2 + 1];
    float aa = Pv - Qn + bias;
    const int* ix = idxl + bb*N_*K_ + n*K_;
    #pragma unroll
    for (int kk = 0; kk < K_; ++kk) {
      int j = ix[kk];
      float v = fmaf(aa + Cl[(rbase + j)*128 + oo*2 + 1], invv, shift);
      best = fmaxf(best, v);
    }
  }
  out[(size_t)(b0 + bb) * D_ + og] = best;
}

extern "C" void kernel_launch(void* const* d_in, const int* in_sizes, int n_in,
                              void* d_out, int out_size, void* d_ws, size_t ws_size,
                              hipStream_t stream)
{
  const float* x      = (const float*)d_in[0];
  const float* conv_w = (const float*)d_in[1];
  const float* conv_b = (const float*)d_in[2];
  const float* gamma  = (const float*)d_in[3];
  const float* beta   = (const float*)d_in[4];
  const float* mean   = (const float*)d_in[5];
  const float* var    = (const float*)d_in[6];

  // workspace: nn_idx 76800 B | Xb bf16 7864320 B | Wn bf16 16777216 B  (24.7 MB)
  int* nn_idx = (int*)d_ws;
  unsigned short* Xb = (unsigned short*)((char*)d_ws + 76800);
  unsigned short* Wn = (unsigned short*)((char*)d_ws + 76800 + (size_t)M_*D_*2);

  prep_kernel<<<B_ + 416, 512, 0, stream>>>(x, conv_w, nn_idx, Xb, Wn);
  fused_gemm<<<dim3(24, 32), 256, 0, stream>>>(
      Xb, Wn, nn_idx, conv_b, gamma, beta, mean, var, (float*)d_out);
}